// Round 2
// baseline (258.397 us; speedup 1.0000x reference)
//
#include <hip/hip_runtime.h>
#include <hip/hip_cooperative_groups.h>

namespace cg = cooperative_groups;

static constexpr int   H         = 4096;
static constexpr int   MAX_STEPS = 16;
static constexpr float EPS       = 0.01f;

__device__ __forceinline__ float wave_reduce(float v) {
    #pragma unroll
    for (int off = 32; off > 0; off >>= 1) v += __shfl_down(v, off);
    return v;
}
__device__ __forceinline__ float sigmoidf(float z) { return 1.f / (1.f + __expf(-z)); }

// ==================== cooperative fused path ====================
static constexpr int TPB_C = 1024;  // 16 waves/block, 1 wave per output row
static constexpr int NB_C  = 256;   // 1 block/CU -> co-residency needs only 1 block/CU (4x headroom vs R1)
// ws layout (floats): h[2][H] | partials[MAX_STEPS][NB_C]
static constexpr int CWS_H    = 0;
static constexpr int CWS_PART = 2 * H;

__global__ void __launch_bounds__(TPB_C, 4)
k_fused(const float* __restrict__ x,     const float* __restrict__ s,
        const float* __restrict__ Wih,   const float* __restrict__ bih,
        const float* __restrict__ Whh,   const float* __restrict__ bhh,
        const float* __restrict__ whalt, const float* __restrict__ bhalt,
        const float* __restrict__ Wout,  const float* __restrict__ bout,
        float* __restrict__ ws,          float* __restrict__ out)
{
    cg::grid_group grid = cg::this_grid();
    __shared__ float sh[H];      // x, then h_in per step, then h_N
    __shared__ float hred[16];
    const int tid = threadIdx.x, lane = tid & 63, wave = tid >> 6;
    const int row = blockIdx.x * 16 + wave;
    float* wsH  = ws + CWS_H;
    float* part = ws + CWS_PART;
    const float bh = bhalt[0];

    // ---- init: v0 = W_ih[:,1:]@x + b_ih + b_hh (lane 0); wih0 = W_ih[row][0] ----
    for (int i = tid; i < H / 4; i += TPB_C)
        ((float4*)sh)[i] = ((const float4*)x)[i];
    __syncthreads();

    // W_ih row stride is H+1 = 4097; columns 1..4096 of this row.
    const long long off0 = (long long)row * (H + 1) + 1;
    const int a = (int)((4 - (off0 & 3)) & 3);      // scalars until 16B alignment
    float acc = 0.f;
    if (lane < a) acc += Wih[off0 + lane] * sh[lane];
    const int nvec = (H - a) >> 2;
    const float4* wv = (const float4*)(Wih + off0 + a);
    for (int i = lane; i < nvec; i += 64) {
        float4 w  = wv[i];
        const int e = a + i * 4;
        acc = fmaf(w.x, sh[e],     acc);
        acc = fmaf(w.y, sh[e + 1], acc);
        acc = fmaf(w.z, sh[e + 2], acc);
        acc = fmaf(w.w, sh[e + 3], acc);
    }
    const int tail  = (H - a) & 3;
    const int tbase = a + nvec * 4;
    if (lane < tail) acc += Wih[off0 + tbase + lane] * sh[tbase + lane];
    acc = wave_reduce(acc);
    float v0 = 0.f, wih0 = 0.f;
    if (lane == 0) {
        v0   = acc + bih[row] + bhh[row];
        wih0 = Wih[(long long)row * (H + 1)];
    }
    __syncthreads();   // x reads from sh done before step 0 overwrites it

    // ---- recurrent loop: h_{t+1} = tanh(v0 + [t==0]wih0 + W_hh@h_t) ----
    int   N   = MAX_STEPS - 1;
    float cum = 0.f;
    for (int t = 0; t < MAX_STEPS; ++t) {
        const float* hin = (t == 0) ? s : (wsH + (size_t)(t & 1) * H);
        for (int i = tid; i < H / 4; i += TPB_C)
            ((float4*)sh)[i] = ((const float4*)hin)[i];
        __syncthreads();

        const float4* Wr = (const float4*)(Whh + (size_t)row * H);
        float4 w[16];
        #pragma unroll
        for (int it = 0; it < 16; ++it) w[it] = Wr[it * 64 + lane];  // 16 loads in flight
        float a2 = 0.f;
        #pragma unroll
        for (int it = 0; it < 16; ++it) {
            float4 hv = ((const float4*)sh)[it * 64 + lane];
            a2 = fmaf(w[it].x, hv.x, a2);
            a2 = fmaf(w[it].y, hv.y, a2);
            a2 = fmaf(w[it].z, hv.z, a2);
            a2 = fmaf(w[it].w, hv.w, a2);
        }
        a2 = wave_reduce(a2);
        if (lane == 0) {
            float pre  = a2 + v0 + (t == 0 ? wih0 : 0.f);
            float hval = tanhf(pre);
            wsH[(size_t)((t + 1) & 1) * H + row] = hval;   // h after step t
            hred[wave] = whalt[row] * hval;
        }
        __syncthreads();
        if (tid == 0) {   // per-block halt partial: write-only, no atomics, no zero-init
            float v = 0.f;
            #pragma unroll
            for (int j2 = 0; j2 < 16; ++j2) v += hred[j2];
            part[t * NB_C + blockIdx.x] = v;
        }
        __threadfence();
        grid.sync();      // h_{t+1} + partials visible device-wide

        // every block reduces the 256 partials in identical order -> uniform decision
        float sl = (tid < NB_C) ? part[t * NB_C + tid] : 0.f;
        sl = wave_reduce(sl);
        if (lane == 0) hred[wave] = sl;
        __syncthreads();
        float sj = 0.f;
        #pragma unroll
        for (int j2 = 0; j2 < 16; ++j2) sj += hred[j2];
        cum += sigmoidf(sj + bh);
        __syncthreads();          // hred reads done before next iter rewrites it
        if (cum >= 1.f - EPS) { N = t; break; }
    }

    // ---- final: out = W_out @ h_N + b_out ; s_new = h_N ; ponder = N ----
    const float* hN = wsH + (size_t)((N + 1) & 1) * H;     // h after step N
    for (int i = tid; i < H / 4; i += TPB_C)
        ((float4*)sh)[i] = ((const float4*)hN)[i];
    __syncthreads();

    const float4* Wr = (const float4*)(Wout + (size_t)row * H);
    float4 w[16];
    #pragma unroll
    for (int it = 0; it < 16; ++it) w[it] = Wr[it * 64 + lane];
    float a3 = 0.f;
    #pragma unroll
    for (int it = 0; it < 16; ++it) {
        float4 hv = ((const float4*)sh)[it * 64 + lane];
        a3 = fmaf(w[it].x, hv.x, a3);
        a3 = fmaf(w[it].y, hv.y, a3);
        a3 = fmaf(w[it].z, hv.z, a3);
        a3 = fmaf(w[it].w, hv.w, a3);
    }
    a3 = wave_reduce(a3);
    if (lane == 0) {
        out[row]     = a3 + bout[row];
        out[H + row] = sh[row];
        if (row == 0) out[2 * H] = (float)N;
    }
}

// ==================== fallback: proven 257us multi-dispatch path ====================
static constexpr int TPB         = 256;
static constexpr int NB          = H / 4;
static constexpr int SLOTS       = 64;
static constexpr int SLOT_STRIDE = 32;

static constexpr int FWS_V0   = 0;
static constexpr int FWS_WIH0 = H;
static constexpr int FWS_TOT  = 2 * H;
static constexpr int FWS_PART = 2 * H + 32;
static constexpr int FWS_H    = FWS_PART + MAX_STEPS * SLOTS * SLOT_STRIDE;

__global__ void __launch_bounds__(TPB)
k_init(const float* __restrict__ x, const float* __restrict__ s,
       const float* __restrict__ Wih, const float* __restrict__ bih,
       const float* __restrict__ bhh, float* __restrict__ ws)
{
    __shared__ float xs[H];
    const int tid = threadIdx.x, lane = tid & 63, wave = tid >> 6;
    const int row = blockIdx.x * 4 + wave;

    for (int i = tid; i < H / 4; i += TPB)
        ((float4*)xs)[i] = ((const float4*)x)[i];
    __syncthreads();

    const long long off0 = (long long)row * (H + 1) + 1;
    const int a = (int)((4 - (off0 & 3)) & 3);
    float acc = 0.f;
    if (lane < a) acc += Wih[off0 + lane] * xs[lane];
    const int nvec = (H - a) >> 2;
    const float4* wv = (const float4*)(Wih + off0 + a);
    for (int i = lane; i < nvec; i += 64) {
        float4 w  = wv[i];
        const int e = a + i * 4;
        acc = fmaf(w.x, xs[e],     acc);
        acc = fmaf(w.y, xs[e + 1], acc);
        acc = fmaf(w.z, xs[e + 2], acc);
        acc = fmaf(w.w, xs[e + 3], acc);
    }
    const int tail  = (H - a) & 3;
    const int tbase = a + nvec * 4;
    if (lane < tail) acc += Wih[off0 + tbase + lane] * xs[tbase + lane];
    acc = wave_reduce(acc);
    if (lane == 0) {
        ws[FWS_V0 + row]   = acc + bih[row] + bhh[row];
        ws[FWS_WIH0 + row] = Wih[(long long)row * (H + 1)];
    }

    const int gid = blockIdx.x * TPB + tid;
    if (gid < H) ws[FWS_H + gid] = s[gid];
    if (gid < 32 + MAX_STEPS * SLOTS * SLOT_STRIDE)
        ws[FWS_TOT + gid] = 0.f;
}

__global__ void __launch_bounds__(TPB, 4)
k_step(int t, const float* __restrict__ Whh, const float* __restrict__ whalt,
       const float* __restrict__ bhalt, float* __restrict__ ws)
{
    const float bh = bhalt[0];

    float cum = 0.f;
    for (int j = 0; j < t - 1; ++j) {
        cum += sigmoidf(ws[FWS_TOT + j] + bh);
        if (cum >= 1.f - EPS) return;
    }
    if (t >= 1) {
        float sj = 0.f;
        const float* p = ws + FWS_PART + (size_t)(t - 1) * (SLOTS * SLOT_STRIDE);
        #pragma unroll
        for (int g = 0; g < SLOTS; ++g) sj += p[g * SLOT_STRIDE];
        if (threadIdx.x == 0) ws[FWS_TOT + (t - 1)] = sj;
        cum += sigmoidf(sj + bh);
        if (cum >= 1.f - EPS) return;
    }

    __shared__ float hs[H];
    __shared__ float hred[4];
    const int tid = threadIdx.x, lane = tid & 63, wave = tid >> 6;
    const float* hin  = ws + FWS_H + (size_t)(t & 1) * H;
    float*       hout = ws + FWS_H + (size_t)((t + 1) & 1) * H;
    for (int i = tid; i < H / 4; i += TPB)
        ((float4*)hs)[i] = ((const float4*)hin)[i];
    __syncthreads();

    const int row = blockIdx.x * 4 + wave;
    const float4* Wr = (const float4*)(Whh + (size_t)row * H);
    float4 w[16];
    #pragma unroll
    for (int it = 0; it < 16; ++it) w[it] = Wr[it * 64 + lane];
    float acc = 0.f;
    #pragma unroll
    for (int it = 0; it < 16; ++it) {
        float4 hv = ((const float4*)hs)[it * 64 + lane];
        acc = fmaf(w[it].x, hv.x, acc);
        acc = fmaf(w[it].y, hv.y, acc);
        acc = fmaf(w[it].z, hv.z, acc);
        acc = fmaf(w[it].w, hv.w, acc);
    }
    acc = wave_reduce(acc);
    if (lane == 0) {
        float pre  = acc + ws[FWS_V0 + row] + (t == 0 ? ws[FWS_WIH0 + row] : 0.f);
        float hval = tanhf(pre);
        hout[row]  = hval;
        hred[wave] = whalt[row] * hval;
    }
    __syncthreads();
    if (tid == 0) {
        float v = hred[0] + hred[1] + hred[2] + hred[3];
        atomicAdd(&ws[FWS_PART + (size_t)t * (SLOTS * SLOT_STRIDE)
                      + (blockIdx.x & (SLOTS - 1)) * SLOT_STRIDE], v);
    }
}

__global__ void __launch_bounds__(TPB, 4)
k_final(const float* __restrict__ Wout, const float* __restrict__ bout,
        const float* __restrict__ bhalt, float* __restrict__ ws,
        float* __restrict__ out)
{
    const float bh = bhalt[0];
    float cum = 0.f;
    int N = MAX_STEPS - 1;
    for (int j = 0; j < MAX_STEPS; ++j) {
        float sj;
        if (j < MAX_STEPS - 1) sj = ws[FWS_TOT + j];
        else {
            sj = 0.f;
            const float* p = ws + FWS_PART + (size_t)(MAX_STEPS - 1) * (SLOTS * SLOT_STRIDE);
            #pragma unroll
            for (int g = 0; g < SLOTS; ++g) sj += p[g * SLOT_STRIDE];
        }
        cum += sigmoidf(sj + bh);
        if (cum >= 1.f - EPS) { N = j; break; }
    }

    __shared__ float hs[H];
    const float* hN = ws + FWS_H + (size_t)((N + 1) & 1) * H;
    const int tid = threadIdx.x, lane = tid & 63, wave = tid >> 6;
    for (int i = tid; i < H / 4; i += TPB)
        ((float4*)hs)[i] = ((const float4*)hN)[i];
    __syncthreads();

    const int row = blockIdx.x * 4 + wave;
    const float4* Wr = (const float4*)(Wout + (size_t)row * H);
    float4 w[16];
    #pragma unroll
    for (int it = 0; it < 16; ++it) w[it] = Wr[it * 64 + lane];
    float acc = 0.f;
    #pragma unroll
    for (int it = 0; it < 16; ++it) {
        float4 hv = ((const float4*)hs)[it * 64 + lane];
        acc = fmaf(w[it].x, hv.x, acc);
        acc = fmaf(w[it].y, hv.y, acc);
        acc = fmaf(w[it].z, hv.z, acc);
        acc = fmaf(w[it].w, hv.w, acc);
    }
    acc = wave_reduce(acc);
    if (lane == 0) {
        out[row]     = acc + bout[row];
        out[H + row] = hs[row];
        if (row == 0) out[2 * H] = (float)N;
    }
}

extern "C" void kernel_launch(void* const* d_in, const int* in_sizes, int n_in,
                              void* d_out, int out_size, void* d_ws, size_t ws_size,
                              hipStream_t stream) {
    const float* x     = (const float*)d_in[0];
    const float* s     = (const float*)d_in[1];
    const float* Wih   = (const float*)d_in[2];
    const float* bih   = (const float*)d_in[3];
    const float* Whh   = (const float*)d_in[4];
    const float* bhh   = (const float*)d_in[5];
    const float* whalt = (const float*)d_in[6];
    const float* bhalt = (const float*)d_in[7];
    const float* Wout  = (const float*)d_in[8];
    const float* bout  = (const float*)d_in[9];
    float* out = (float*)d_out;
    float* ws  = (float*)d_ws;

    // Host-side-only capability probe (no stream ops -> graph-capture safe), cached.
    static int use_coop = -1;
    if (use_coop < 0) {
        int dev = 0;  (void)hipGetDevice(&dev);
        int coop = 0; (void)hipDeviceGetAttribute(&coop, hipDeviceAttributeCooperativeLaunch, dev);
        int ncu = 0;  (void)hipDeviceGetAttribute(&ncu, hipDeviceAttributeMultiprocessorCount, dev);
        int maxb = 0;
        (void)hipOccupancyMaxActiveBlocksPerMultiprocessor(&maxb, k_fused, TPB_C, 0);
        use_coop = (coop != 0 && (long long)maxb * (long long)ncu >= NB_C) ? 1 : 0;
    }

    if (use_coop == 1) {
        void* args[] = { &x, &s, &Wih, &bih, &Whh, &bhh, &whalt, &bhalt,
                         &Wout, &bout, &ws, &out };
        hipError_t e = hipLaunchCooperativeKernel((const void*)k_fused, dim3(NB_C),
                                                  dim3(TPB_C), args, 0, stream);
        if (e == hipSuccess) return;
        use_coop = 0;   // launch rejected synchronously -> fall through to proven path
    }

    k_init<<<NB, TPB, 0, stream>>>(x, s, Wih, bih, bhh, ws);
    for (int t = 0; t < MAX_STEPS; ++t)
        k_step<<<NB, TPB, 0, stream>>>(t, Whh, whalt, bhalt, ws);
    k_final<<<NB, TPB, 0, stream>>>(Wout, bout, bhalt, ws, out);
}